// Round 1
// baseline (90.116 us; speedup 1.0000x reference)
//
#include <hip/hip_runtime.h>
#include <hip/hip_bf16.h>

#define KHH 7
#define KWW 7
#define EHH 5
#define EWW 5
#define EPSF 1e-7f
#define B_ 8
#define H_ 64
#define W_ 64
#define C_ 32
#define HO 58
#define WO 58
#define NPIX (B_*HO*WO)   // 26912
#define NF 64
#define KDIM 800          // EH*EW*C

typedef __bf16 v8bf __attribute__((ext_vector_type(8)));
typedef __bf16 v4bf __attribute__((ext_vector_type(4)));
typedef float  v4f  __attribute__((ext_vector_type(4)));

// ---------------- kernel 0a: channel-sum image S[b][h][w] ----------------
__global__ void k_chansum(const float* __restrict__ x, float* __restrict__ S) {
    int p = blockIdx.x*256 + threadIdx.x;
    if (p >= B_*H_*W_) return;
    const float4* xp = (const float4*)(x + (size_t)p*C_);
    float s = 0.f;
#pragma unroll
    for (int q = 0; q < 8; q++) { float4 v = xp[q]; s += v.x+v.y+v.z+v.w; }
    S[p] = s;
}

// ---------------- kernel 0b: pack W into MFMA B-fragment order, bf16 ------
// Wp[((nt*25+kb)*64+lane)*8+j] = W[f=nt*16+(lane&15)][k=kb*32+(lane>>4)*8+j]
__global__ void k_wpack(const float* __restrict__ W, __bf16* __restrict__ Wp) {
    int t = blockIdx.x*256 + threadIdx.x;   // 51200 total
    int j = t & 7; int lane = (t >> 3) & 63; int rest = t >> 9;
    int kb = rest % 25; int nt = rest / 25;
    int f = nt*16 + (lane & 15);
    int k = kb*32 + (lane >> 4)*8 + j;
    Wp[t] = (__bf16)W[f*KDIM + k];
}

// ---------------- kernel 1: per-pixel affine params ----------------------
__global__ void k_params(const float* __restrict__ S, float4* __restrict__ prm) {
    int pix = blockIdx.x*256 + threadIdx.x;
    if (pix >= NPIX) return;
    int b  = pix / (HO*WO); int rem = pix % (HO*WO);
    int ho = rem / WO;      int wo  = rem % WO;
    const float* Sp = S + (b*H_ + ho)*W_ + wo;
    float den = 0.f, crn = 0.f, ccn = 0.f;
#pragma unroll
    for (int i = 0; i < 7; i++) {
#pragma unroll
        for (int j = 0; j < 7; j++) {
            float v = Sp[i*W_ + j];
            den += v; crn += v*(float)i; ccn += v*(float)j;
        }
    }
    float dt = den + EPSF;
    float cr = crn/dt - 3.0f;
    float cc = ccn/dt - 3.0f;
    float ang = atan2f(cr, cc + EPSF);
    float c = cosf(ang), s = sinf(ang);
    const float scale = 1.0f + EPSF;
    float xo = (6.0f - (c*6.0f - s*6.0f))*0.5f;
    float yo = (6.0f - (s*6.0f + c*6.0f))*0.5f;
    prm[pix] = make_float4(c/scale, s/scale, xo/scale, yo/scale);
}

// ---------------- kernel 2: rotate + GEMM (fused) ------------------------
__global__ __launch_bounds__(256)
void k_main(const float* __restrict__ x, const v8bf* __restrict__ Wp,
            const float* __restrict__ bias, const float4* __restrict__ prm,
            float* __restrict__ out) {
    __shared__ float xt[7][22][32];         // 19,712 B
    __shared__ __bf16 rot[16][KDIM];        // 25,600 B
    __shared__ float4 pp[16];

    int tid = threadIdx.x;
    int wt = blockIdx.x, ho = blockIdx.y, b = blockIdx.z;
    int wo0 = wt*16;
    int npx = WO - wo0; if (npx > 16) npx = 16;   // 16 or 10
    int ncols = npx + 6;                           // 22 or 16

    // stage x tile: rows ho..ho+6, cols wo0..wo0+ncols-1, all 32 ch
    const float* xb = x + (size_t)((b*H_ + ho)*W_ + wo0)*C_;
    int total4 = 7*ncols*8;
    for (int e = tid; e < total4; e += 256) {
        int r = e/(ncols*8); int rem = e - r*(ncols*8);
        int cc = rem >> 3;   int q = rem & 7;
        *(float4*)&xt[r][cc][q*4] = *(const float4*)&xb[(r*W_ + cc)*C_ + q*4];
    }
    int pixbase = (b*HO + ho)*WO + wo0;
    if (tid < npx) pp[tid] = prm[pixbase + tid];
    __syncthreads();

    // phase 3: rotated+cropped patch -> bf16 in LDS. 4 channels per item.
    int tot = npx*200;   // npx * 25 positions * 8 ch-quads
    for (int e = tid; e < tot; e += 256) {
        int px = e/200; int r4 = e - px*200;
        int pos = r4 >> 3; int ch4 = (r4 & 7)*4;
        int py = pos/5; int yy = py + 1; int xx = (pos - py*5) + 1;
        float4 p = pp[px];
        float xin = p.x*(float)xx - p.y*(float)yy + p.z;
        float yin = p.y*(float)xx + p.x*(float)yy + p.w;
        float x0f = floorf(xin), y0f = floorf(yin);
        float wx1 = xin - x0f, wx0 = 1.0f - wx1;
        float wy1 = yin - y0f, wy0 = 1.0f - wy1;
        int ix0 = (int)x0f, iy0 = (int)y0f;
        int ix1 = ix0 + 1,  iy1 = iy0 + 1;
        float a0=0.f, a1=0.f, a2=0.f, a3=0.f;
        auto corner = [&](int yi, int xi, float wgt) {
            bool valid = (xi >= 0) & (xi < KWW) & (yi >= 0) & (yi < KHH);
            float wv = valid ? wgt : 0.0f;
            int cy = yi < 0 ? 0 : (yi > 6 ? 6 : yi);
            int cx = xi < 0 ? 0 : (xi > 6 ? 6 : xi);
            float4 v = *(const float4*)&xt[cy][px + cx][ch4];
            a0 += wv*v.x; a1 += wv*v.y; a2 += wv*v.z; a3 += wv*v.w;
        };
        corner(iy0, ix0, wy0*wx0);
        corner(iy0, ix1, wy0*wx1);
        corner(iy1, ix0, wy1*wx0);
        corner(iy1, ix1, wy1*wx1);
        v4bf o; o[0]=(__bf16)a0; o[1]=(__bf16)a1; o[2]=(__bf16)a2; o[3]=(__bf16)a3;
        *(v4bf*)&rot[px][pos*32 + ch4] = o;
    }
    __syncthreads();

    // phase 4: MFMA 16 pixels x 16 filters per wave, K=800
    int wv = tid >> 6; int lane = tid & 63;
    int m = lane & 15; int q = lane >> 4;
    v4f acc = {0.f, 0.f, 0.f, 0.f};
    const v8bf* wp = Wp + (size_t)wv*25*64;
#pragma unroll
    for (int kb = 0; kb < 25; kb++) {
        v8bf a = *(const v8bf*)&rot[m][kb*32 + q*8];
        v8bf bf = wp[kb*64 + lane];
        acc = __builtin_amdgcn_mfma_f32_16x16x32_bf16(a, bf, acc, 0, 0, 0);
    }
    int n = lane & 15; int f = wv*16 + n;
    float bv = bias[f];
#pragma unroll
    for (int r = 0; r < 4; r++) {
        int px = q*4 + r;   // C/D row = (lane>>4)*4 + reg
        if (px < npx) out[(size_t)(pixbase + px)*NF + f] = acc[r] + bv;
    }
}

extern "C" void kernel_launch(void* const* d_in, const int* in_sizes, int n_in,
                              void* d_out, int out_size, void* d_ws, size_t ws_size,
                              hipStream_t stream) {
    const float* x    = (const float*)d_in[0];
    const float* W    = (const float*)d_in[1];
    const float* bias = (const float*)d_in[2];
    float* out = (float*)d_out;
    char* ws = (char*)d_ws;
    float*  S   = (float*)ws;                              // 131,072 B
    float4* prm = (float4*)(ws + 131072);                  // 430,592 B
    __bf16* Wp  = (__bf16*)(ws + 131072 + 430592);         // 102,400 B

    k_chansum<<<dim3((B_*H_*W_)/256), 256, 0, stream>>>(x, S);
    k_wpack<<<dim3(200), 256, 0, stream>>>(W, Wp);
    k_params<<<dim3((NPIX + 255)/256), 256, 0, stream>>>(S, prm);
    k_main<<<dim3(4, HO, B_), 256, 0, stream>>>(x, (const v8bf*)Wp, bias, prm, out);
}